// Round 12
// baseline (99.882 us; speedup 1.0000x reference)
//
#include <hip/hip_runtime.h>

// Problem dims (fixed by reference setup_inputs)
#define BDIM 256
#define IDIM 1024
#define ODIM 1024

#define TILE_O 64   // outputs per block (one per lane)
#define TILE_B 4    // batch rows per block (all 4 in each thread)
#define NW 8        // waves per block, each owns an i-eighth
#define QLEN (IDIM / NW)   // 128 i per wave

#if __has_builtin(__builtin_amdgcn_exp2f)
#define FAST_EXP2(v) __builtin_amdgcn_exp2f(v)
#else
#define FAST_EXP2(v) exp2f(v)
#endif

__global__ __launch_bounds__(512, 8)
void stl_kernel(const float* __restrict__ x,
                const float* __restrict__ w,
                const float* __restrict__ bias,
                float* __restrict__ out) {
  __shared__ float xs[TILE_B][IDIM];   // 16 KB: 4 x rows, prescaled by log2e
  __shared__ float ps[NW][8][TILE_O];  // 16 KB: per-wave partials, lane-major

  const int tx = threadIdx.x;          // 0..63 -> output column (lane)
  const int ty = threadIdx.y;          // 0..7  -> i-eighth (one wave each)
  const int tid = ty * 64 + tx;
  const int o0 = blockIdx.x * TILE_O;
  const int b0 = blockIdx.y * TILE_B;

  const float LOG2E = 1.4426950408889634f;  // folds 1/TEMPERATURE too

  // ---- Stage 4 x rows once (coalesced, prescaled). Barrier #1. ----
#pragma unroll
  for (int k = 0; k < 2; ++k) {
    int f = tid + k * 512;             // 0..1023 float4s
    int row = f >> 8;                  // 256 float4 per row
    int col = f & 255;
    float4 v = ((const float4*)(x + (size_t)(b0 + row) * IDIM))[col];
    v.x *= LOG2E; v.y *= LOG2E; v.z *= LOG2E; v.w *= LOG2E;
    ((float4*)(&xs[row][0]))[col] = v;
  }
  __syncthreads();

  // ---- Barrier-free main loop ----
  // w addressing: uniform base pointer (scalar pipe) + lane offset (VGPR)
  //   -> global_load_dword v, v_ofs, s[base]; no per-load 64-bit VGPR adds.
  const int qbase = ty * QLEN;
  const int vidx = o0 + tx;            // lane part of the w index

  float num[TILE_B] = {0, 0, 0, 0};
  float den[TILE_B] = {0, 0, 0, 0};

  // Prefetch group 0 (8 w values, one 256B coalesced load each).
  float wv[8];
#pragma unroll
  for (int u = 0; u < 8; ++u)
    wv[u] = (w + (size_t)(qbase + u) * ODIM)[vidx];

  for (int j = 0; j < QLEN; j += 8) {
    // Rotate: capture current group, then issue next group's loads
    // (wrap-indexed on the last iteration to stay in-bounds; values unused).
    float wc[8];
#pragma unroll
    for (int u = 0; u < 8; ++u) wc[u] = wv[u];
    {
      const int jn = (j + 8) & (QLEN - 1);   // uniform, scalar-pipe AND
#pragma unroll
      for (int u = 0; u < 8; ++u)
        wv[u] = (w + (size_t)(qbase + jn + u) * ODIM)[vidx];
    }

#pragma unroll
    for (int r = 0; r < TILE_B; ++r) {
      float4 x0 = *(const float4*)(&xs[r][qbase + j]);       // broadcast b128
      float4 x1 = *(const float4*)(&xs[r][qbase + j + 4]);   // broadcast b128
      const float xv[8] = {x0.x, x0.y, x0.z, x0.w, x1.x, x1.y, x1.z, x1.w};
#pragma unroll
      for (int u = 0; u < 8; ++u) {
        float p = xv[u] * wc[u];                 // v_mul_f32 (p = log2e*z)
        float t = FAST_EXP2(__builtin_fabsf(p)); // v_exp_f32 with |.| modifier
        num[r] = __builtin_fmaf(p, t, num[r]);   // v_fmac_f32
        den[r] += t;                             // v_add_f32
      }
    }
  }

  // ---- Cross-wave combine (barrier #2), conflict-free lane-major layout ----
#pragma unroll
  for (int r = 0; r < TILE_B; ++r) {
    ps[ty][r][tx] = num[r];
    ps[ty][4 + r][tx] = den[r];
  }
  __syncthreads();

  // Distributed epilogue: waves 0..3 each finish one batch row.
  if (ty < TILE_B) {
    float n = 0.0f, d = 0.0f;
#pragma unroll
    for (int q = 0; q < NW; ++q) {
      n += ps[q][ty][tx];          // stride-1 lanes: conflict-free
      d += ps[q][4 + ty][tx];
    }
    const float LN2 = 0.6931471805599453f;
    const float scale = (float)IDIM * LN2;   // undo log2e, apply n
    const int o = o0 + tx;
    out[(size_t)(b0 + ty) * ODIM + o] = scale * n / d + bias[o];
  }
}

extern "C" void kernel_launch(void* const* d_in, const int* in_sizes, int n_in,
                              void* d_out, int out_size, void* d_ws, size_t ws_size,
                              hipStream_t stream) {
  const float* x = (const float*)d_in[0];    // [256,1024] f32
  const float* w = (const float*)d_in[1];    // [1024,1024] f32
  const float* b = (const float*)d_in[2];    // [1024] f32
  float* out = (float*)d_out;                // [256,1024] f32

  dim3 grid(ODIM / TILE_O, BDIM / TILE_B);   // (16, 64) = 1024 blocks = 4/CU
  dim3 block(64, NW);                        // 512 threads = 8 waves
  stl_kernel<<<grid, block, 0, stream>>>(x, w, b, out);
}